// Round 1
// baseline (4135.394 us; speedup 1.0000x reference)
//
#include <hip/hip_runtime.h>
#include <math.h>

#define HH 4096
#define WW 4096
#define NB 64      // blocks (pipeline stages)
#define RPB 64     // rows per block == lanes per block (1 wave)
#define U 8        // column unroll / prefetch group

// halo slot layout in d_ws: for block b, slot jj (0..WW-1) holds the block's
// bottom-2-row activations *after* column jj-1 (jj=0 holds the initial x).
// Each entry: low 32 = float bits, high 32 = tag (jj+1). Poison 0xAAAAAAAA
// never equals a valid tag (1..4096), so unwritten slots always mismatch.
// Size: NB * WW * 2 * 8B = 4 MiB.

struct Pref {
    float w8[U], b8[U];
    float wa1[U], wa2[U];              // w rows r0-1, r0-2 (lanes<2 only)
    unsigned long long h0[U], h1[U];   // halo entries (lanes<2 only)
};

__global__ __launch_bounds__(64, 1) void neural_grid_scan(
    const float* __restrict__ x, const float* __restrict__ w,
    const float* __restrict__ bb, float* __restrict__ out,
    unsigned long long* __restrict__ halo)
{
    const int blk  = blockIdx.x;
    const int lane = threadIdx.x;
    const int row  = blk * RPB + lane;

    const float* wp  = w  + (size_t)row * WW;
    const float* bp  = bb + (size_t)row * WW;
    const float* wl1 = w + (size_t)(row - 1) * WW;  // valid only lane<2 && blk>0
    const float* wl2 = w + (size_t)(row - 2) * WW;

    float a = x[row];

    // publish initial state (column -1 == x) into slot 0, tag 1
    if (lane >= RPB - 2) {
        unsigned long long v = (1ULL << 32) | (unsigned long long)__float_as_uint(a);
        __hip_atomic_store(&halo[((size_t)blk * WW + 0) * 2 + (lane - (RPB - 2))], v,
                           __ATOMIC_RELAXED, __HIP_MEMORY_SCOPE_AGENT);
    }

    const unsigned long long* hsrc = halo + ((size_t)(blk - 1) * WW) * 2;

    auto loadGroup = [&](int j, Pref& P) {
        *(float4*)&P.w8[0] = *(const float4*)(wp + j);
        *(float4*)&P.w8[4] = *(const float4*)(wp + j + 4);
        *(float4*)&P.b8[0] = *(const float4*)(bp + j);
        *(float4*)&P.b8[4] = *(const float4*)(bp + j + 4);
        if (lane < 2) {
            if (blk > 0) {
                *(float4*)&P.wa1[0] = *(const float4*)(wl1 + j);
                *(float4*)&P.wa1[4] = *(const float4*)(wl1 + j + 4);
                *(float4*)&P.wa2[0] = *(const float4*)(wl2 + j);
                *(float4*)&P.wa2[4] = *(const float4*)(wl2 + j + 4);
#pragma unroll
                for (int k = 0; k < U; ++k) {
                    P.h0[k] = __hip_atomic_load(&hsrc[(size_t)(j + k) * 2 + 0],
                                                __ATOMIC_RELAXED, __HIP_MEMORY_SCOPE_AGENT);
                    P.h1[k] = __hip_atomic_load(&hsrc[(size_t)(j + k) * 2 + 1],
                                                __ATOMIC_RELAXED, __HIP_MEMORY_SCOPE_AGENT);
                }
            } else {
#pragma unroll
                for (int k = 0; k < U; ++k) {
                    P.wa1[k] = 0.f; P.wa2[k] = 0.f; P.h0[k] = 0; P.h1[k] = 0;
                }
            }
        }
    };

    Pref cur, nxt;
    loadGroup(0, cur);

    for (int j = 0; j < WW; j += U) {
        if (j + U < WW) loadGroup(j + U, nxt);
#pragma unroll
        for (int k = 0; k < U; ++k) {
            const int col = j + k;
            float wj = cur.w8[k];
            float bj = cur.b8[k];
            float am1 = __shfl_up(a, 1);
            float am2 = __shfl_up(a, 2);
            float wm1 = __shfl_up(wj, 1);
            float wm2 = __shfl_up(wj, 2);
            if (lane < 2) {
                if (blk > 0) {
                    const unsigned tagexp = (unsigned)(col + 1);
                    unsigned long long v1 = cur.h1[k];
                    while ((unsigned)(v1 >> 32) != tagexp) {
                        __builtin_amdgcn_s_sleep(1);
                        v1 = __hip_atomic_load(&hsrc[(size_t)col * 2 + 1],
                                               __ATOMIC_RELAXED, __HIP_MEMORY_SCOPE_AGENT);
                    }
                    unsigned long long v0 = cur.h0[k];
                    while ((unsigned)(v0 >> 32) != tagexp) {
                        __builtin_amdgcn_s_sleep(1);
                        v0 = __hip_atomic_load(&hsrc[(size_t)col * 2 + 0],
                                               __ATOMIC_RELAXED, __HIP_MEMORY_SCOPE_AGENT);
                    }
                    float aup1 = __uint_as_float((unsigned)(v1 & 0xffffffffu)); // row r0-1
                    float aup2 = __uint_as_float((unsigned)(v0 & 0xffffffffu)); // row r0-2
                    if (lane == 0) { am1 = aup1; am2 = aup2; wm1 = cur.wa1[k]; wm2 = cur.wa2[k]; }
                    else           { am2 = aup1; wm2 = cur.wa1[k]; }
                } else {
                    if (lane == 0) { am1 = 0.f; am2 = 0.f; }
                    else           { am2 = 0.f; }
                }
            }
            float z = fmaf(am2, wm2, fmaf(am1, wm1, fmaf(a, wj, bj)));
            a = sinf(z);
            if (lane >= RPB - 2) {
                const int jj = col + 1;
                if (jj < WW) {
                    unsigned long long v = ((unsigned long long)(unsigned)(jj + 1) << 32)
                                         | (unsigned long long)__float_as_uint(a);
                    __hip_atomic_store(&halo[((size_t)blk * WW + jj) * 2 + (lane - (RPB - 2))], v,
                                       __ATOMIC_RELAXED, __HIP_MEMORY_SCOPE_AGENT);
                }
            }
        }
        cur = nxt;
    }

    out[row] = a;
}

extern "C" void kernel_launch(void* const* d_in, const int* in_sizes, int n_in,
                              void* d_out, int out_size, void* d_ws, size_t ws_size,
                              hipStream_t stream) {
    const float* x = (const float*)d_in[0];
    const float* w = (const float*)d_in[1];
    const float* b = (const float*)d_in[2];
    float* out = (float*)d_out;
    unsigned long long* halo = (unsigned long long*)d_ws;
    neural_grid_scan<<<dim3(NB), dim3(64), 0, stream>>>(x, w, b, out, halo);
}